// Round 3
// baseline (425.385 us; speedup 1.0000x reference)
//
#include <hip/hip_runtime.h>
#include <hip/hip_bf16.h>

// GAT layer, N=8192, F=128.
//   k0: u = W@a1, v = W@a2                     (fp32, trivial)
//   k1: Wh = h@W -> WhT (bf16 [F][N]); e_src = h@u, e_dst = h@v (fp32)
//   k2: fused masked-softmax(P) @ Wh. Block = 128 rows x 1024-k seg.
//       Dense coalesced adj reads, P via dbuf XOR-swizzled LDS, 1 barrier
//       per 64-k chunk, 16 MFMA/chunk/wave. Per-seg partial num/den -> ws.
//   k3: out[i][:] = (sum_seg num)/ (sum_seg den)
//
// ws: [0,2MB) WhT | u,v,e_src,e_dst | num_ws 8x4MB @4MB | den_ws 8x32KB @36MB

#define NN 8192
#define FF 128
#define SEGS 8
#define KSEG (NN / SEGS)     // 1024
#define KC 64
#define NCH (KSEG / KC)      // 16

typedef __bf16 bf16x8 __attribute__((ext_vector_type(8)));
typedef float floatx4 __attribute__((ext_vector_type(4)));

__device__ __forceinline__ unsigned short f2b(float f) {
    unsigned int u = __float_as_uint(f);
    return (unsigned short)((u + 0x7FFFu + ((u >> 16) & 1u)) >> 16);
}
__device__ __forceinline__ unsigned int pk2(float a, float b) {
    return (unsigned int)f2b(a) | ((unsigned int)f2b(b) << 16);
}

// ---------------- k0 ----------------
__global__ __launch_bounds__(128) void k0_uv(const float* __restrict__ W,
                                             const float* __restrict__ a,
                                             float* __restrict__ u,
                                             float* __restrict__ v) {
    int k = blockIdx.x, t = threadIdx.x;
    float wv = W[k * FF + t];
    float p1 = wv * a[t];
    float p2 = wv * a[FF + t];
    for (int off = 32; off; off >>= 1) {
        p1 += __shfl_down(p1, off);
        p2 += __shfl_down(p2, off);
    }
    __shared__ float r[4];
    if ((t & 63) == 0) { r[(t >> 6) * 2] = p1; r[(t >> 6) * 2 + 1] = p2; }
    __syncthreads();
    if (t == 0) { u[k] = r[0] + r[2]; v[k] = r[1] + r[3]; }
}

// ---------------- k1 ----------------
__global__ __launch_bounds__(256) void k1_wh(const float* __restrict__ h,
                                             const float* __restrict__ W,
                                             const float* __restrict__ u,
                                             const float* __restrict__ v,
                                             unsigned short* __restrict__ WhT,
                                             float* __restrict__ e_src,
                                             float* __restrict__ e_dst) {
    __shared__ float hL[32 * 132];
    __shared__ float wL[128 * 132];
    __shared__ float uL[128], vL[128];
    __shared__ unsigned short tL[128 * 40];

    int t = threadIdx.x;
    int i0 = blockIdx.x * 32;

    {
        int row = t >> 3, c = (t & 7) * 16;
        const float4* s = (const float4*)&h[(i0 + row) * FF + c];
        float4* d = (float4*)&hL[row * 132 + c];
        #pragma unroll
        for (int j = 0; j < 4; j++) d[j] = s[j];
    }
    {
        int row = t >> 1, c = (t & 1) * 64;
        const float4* s = (const float4*)&W[row * FF + c];
        float4* d = (float4*)&wL[row * 132 + c];
        #pragma unroll
        for (int j = 0; j < 16; j++) d[j] = s[j];
    }
    if (t < 128) { uL[t] = u[t]; vL[t] = v[t]; }
    __syncthreads();

    int r0 = (t & 7) * 4;
    int c0 = (t >> 3) * 4;
    float acc[4][4] = {};
    for (int k0 = 0; k0 < 128; k0 += 4) {
        float4 hr[4], wr[4];
        #pragma unroll
        for (int i = 0; i < 4; i++) hr[i] = *(const float4*)&hL[(r0 + i) * 132 + k0];
        #pragma unroll
        for (int i = 0; i < 4; i++) wr[i] = *(const float4*)&wL[(k0 + i) * 132 + c0];
        #pragma unroll
        for (int kj = 0; kj < 4; kj++) {
            #pragma unroll
            for (int ri = 0; ri < 4; ri++) {
                float hvv = ((const float*)&hr[ri])[kj];
                const float* wvv = (const float*)&wr[kj];
                #pragma unroll
                for (int cj = 0; cj < 4; cj++) acc[ri][cj] = fmaf(hvv, wvv[cj], acc[ri][cj]);
            }
        }
    }
    #pragma unroll
    for (int ri = 0; ri < 4; ri++)
        #pragma unroll
        for (int cj = 0; cj < 4; cj++)
            tL[(c0 + cj) * 40 + r0 + ri] = f2b(acc[ri][cj]);
    __syncthreads();

    if (t < 64) {
        int row = t & 31;
        const float* sv = (t < 32) ? uL : vL;
        float s = 0.f;
        for (int k = 0; k < 128; k += 4) {
            float4 h4 = *(const float4*)&hL[row * 132 + k];
            float4 s4 = *(const float4*)&sv[k];
            s = fmaf(h4.x, s4.x, s); s = fmaf(h4.y, s4.y, s);
            s = fmaf(h4.z, s4.z, s); s = fmaf(h4.w, s4.w, s);
        }
        (t < 32 ? e_src : e_dst)[i0 + row] = s;
    }
    {
        int f = t & 127, half = t >> 7;
        const uint4* s = (const uint4*)&tL[f * 40 + half * 16];
        uint4* d = (uint4*)&WhT[f * NN + i0 + half * 16];
        d[0] = s[0]; d[1] = s[1];
    }
}

// ---------------- k2 ----------------
__device__ __forceinline__ float mask_w(int a, float x) {
    float l = fmaxf(x, 0.2f * x);
    return a > 0 ? __expf(l) : 0.f;
}

__global__ __launch_bounds__(512, 4) void k2_gat(const int* __restrict__ adj,
                                                 const unsigned short* __restrict__ WhT,
                                                 const float* __restrict__ e_src,
                                                 const float* __restrict__ e_dst,
                                                 float* __restrict__ num_ws,
                                                 float* __restrict__ den_ws) {
    __shared__ unsigned short Pt[2][128 * 64];   // 16 KB each, XOR-swizzled

    int t = threadIdx.x;
    int bx = blockIdx.x;
    int ib = bx >> 3, seg = bx & 7;
    int i0 = ib * 128;
    int jb = seg * KSEG;

    // ---- producer mapping: row = t>>2, 16 contiguous cols ----
    int pr = t >> 2;
    int pc = (t & 3) * 16;
    int r7 = pr & 7;
    int g0 = (t & 3) * 2;                        // logical 16B-block pair
    float es = e_src[i0 + pr];
    const int*   Ab = adj + (size_t)(i0 + pr) * NN + jb + pc;
    const float* Eb = e_dst + jb + pc;
    int wlo = pr * 64 + (((g0 + 0) ^ r7) << 3);  // short offsets
    int whi = pr * 64 + (((g0 + 1) ^ r7) << 3);

    // ---- consumer mapping ----
    int lane = t & 63, wave = t >> 6;
    int mg = wave & 3, ng = wave >> 2;           // 4 row-groups x 2 col-groups
    int mrow = lane & 15, quad = lane >> 4;

    const unsigned short* Bp[4];
    #pragma unroll
    for (int bn = 0; bn < 4; bn++)
        Bp[bn] = WhT + (size_t)(ng * 64 + bn * 16 + mrow) * NN + jb + quad * 8;

    // A-frag short offsets within P tile: row, logical block ks*4+quad
    int arow[2];
    arow[0] = mg * 32 + mrow;
    arow[1] = mg * 32 + 16 + mrow;
    int aoff[2][2];
    #pragma unroll
    for (int a = 0; a < 2; a++)
        #pragma unroll
        for (int ks = 0; ks < 2; ks++)
            aoff[a][ks] = arow[a] * 64 + (((ks * 4 + quad) ^ (arow[a] & 7)) << 3);

    floatx4 acc[2][4] = {};
    float dsum = 0.f;

    // prefetch chunk 0 adj
    int4 av[4];
    #pragma unroll
    for (int j = 0; j < 4; j++) av[j] = *(const int4*)(Ab + 4 * j);

    for (int ch = 0; ch < NCH; ch++) {
        // ---- produce P chunk ch ----
        unsigned short* buf = Pt[ch & 1];
        float4 ev0 = *(const float4*)(Eb + ch * KC);
        float4 ev1 = *(const float4*)(Eb + ch * KC + 4);
        float4 ev2 = *(const float4*)(Eb + ch * KC + 8);
        float4 ev3 = *(const float4*)(Eb + ch * KC + 12);
        float w[16];
        w[0]  = mask_w(av[0].x, es + ev0.x);
        w[1]  = mask_w(av[0].y, es + ev0.y);
        w[2]  = mask_w(av[0].z, es + ev0.z);
        w[3]  = mask_w(av[0].w, es + ev0.w);
        w[4]  = mask_w(av[1].x, es + ev1.x);
        w[5]  = mask_w(av[1].y, es + ev1.y);
        w[6]  = mask_w(av[1].z, es + ev1.z);
        w[7]  = mask_w(av[1].w, es + ev1.w);
        w[8]  = mask_w(av[2].x, es + ev2.x);
        w[9]  = mask_w(av[2].y, es + ev2.y);
        w[10] = mask_w(av[2].z, es + ev2.z);
        w[11] = mask_w(av[2].w, es + ev2.w);
        w[12] = mask_w(av[3].x, es + ev3.x);
        w[13] = mask_w(av[3].y, es + ev3.y);
        w[14] = mask_w(av[3].z, es + ev3.z);
        w[15] = mask_w(av[3].w, es + ev3.w);
        #pragma unroll
        for (int j = 0; j < 16; j++) dsum += w[j];
        uint4 lo = make_uint4(pk2(w[0], w[1]), pk2(w[2], w[3]),
                              pk2(w[4], w[5]), pk2(w[6], w[7]));
        uint4 hi = make_uint4(pk2(w[8], w[9]), pk2(w[10], w[11]),
                              pk2(w[12], w[13]), pk2(w[14], w[15]));
        *(uint4*)&buf[wlo] = lo;
        *(uint4*)&buf[whi] = hi;

        // prefetch next chunk's adj (stays in flight across the barrier)
        int nxt = (ch + 1 < NCH) ? (ch + 1) * KC : 0;
        #pragma unroll
        for (int j = 0; j < 4; j++) av[j] = *(const int4*)(Ab + nxt + 4 * j);

        // B fragments ks=0 (global, L2-resident; no LDS dependency)
        bf16x8 b0[4];
        #pragma unroll
        for (int bn = 0; bn < 4; bn++) b0[bn] = *(const bf16x8*)(Bp[bn] + ch * KC);

        __syncthreads();   // P chunk visible; prior reads of this buffer done

        const unsigned short* rbuf = Pt[ch & 1];
        bf16x8 A0[2], A1[2];
        #pragma unroll
        for (int a = 0; a < 2; a++) A0[a] = *(const bf16x8*)&rbuf[aoff[a][0]];
        #pragma unroll
        for (int a = 0; a < 2; a++) A1[a] = *(const bf16x8*)&rbuf[aoff[a][1]];

        bf16x8 b1[4];
        #pragma unroll
        for (int bn = 0; bn < 4; bn++) b1[bn] = *(const bf16x8*)(Bp[bn] + ch * KC + 32);

        #pragma unroll
        for (int a = 0; a < 2; a++)
            #pragma unroll
            for (int bn = 0; bn < 4; bn++)
                acc[a][bn] = __builtin_amdgcn_mfma_f32_16x16x32_bf16(A0[a], b0[bn], acc[a][bn], 0, 0, 0);
        #pragma unroll
        for (int a = 0; a < 2; a++)
            #pragma unroll
            for (int bn = 0; bn < 4; bn++)
                acc[a][bn] = __builtin_amdgcn_mfma_f32_16x16x32_bf16(A1[a], b1[bn], acc[a][bn], 0, 0, 0);
    }

    // ---- denominator: reduce 4 producer-threads per row ----
    dsum += __shfl_xor(dsum, 1);
    dsum += __shfl_xor(dsum, 2);
    if ((t & 3) == 0) den_ws[seg * NN + i0 + pr] = dsum;

    // ---- numerator partials: plain stores to this seg's slice ----
    float* np = num_ws + (size_t)seg * NN * FF;
    #pragma unroll
    for (int a = 0; a < 2; a++)
        #pragma unroll
        for (int bn = 0; bn < 4; bn++)
            #pragma unroll
            for (int r = 0; r < 4; r++) {
                int row = mg * 32 + a * 16 + quad * 4 + r;
                int col = ng * 64 + bn * 16 + mrow;
                np[(size_t)(i0 + row) * FF + col] = acc[a][bn][r];
            }
}

// ---------------- k3: merge seg partials, divide ----------------
__global__ __launch_bounds__(256) void k3_merge(const float* __restrict__ num_ws,
                                                const float* __restrict__ den_ws,
                                                float* __restrict__ out) {
    int idx = blockIdx.x * 256 + threadIdx.x;
    int i = idx >> 5;
    int c = (idx & 31) << 2;
    float4 s = make_float4(0.f, 0.f, 0.f, 0.f);
    float d = 0.f;
    #pragma unroll
    for (int sg = 0; sg < SEGS; sg++) {
        float4 vv = *(const float4*)&num_ws[(size_t)sg * NN * FF + (size_t)i * FF + c];
        s.x += vv.x; s.y += vv.y; s.z += vv.z; s.w += vv.w;
        d += den_ws[sg * NN + i];
    }
    float r = 1.0f / d;
    s.x *= r; s.y *= r; s.z *= r; s.w *= r;
    *(float4*)&out[(size_t)i * FF + c] = s;
}

extern "C" void kernel_launch(void* const* d_in, const int* in_sizes, int n_in,
                              void* d_out, int out_size, void* d_ws, size_t ws_size,
                              hipStream_t stream) {
    const float* h   = (const float*)d_in[0];
    const int*   adj = (const int*)d_in[1];
    const float* W   = (const float*)d_in[2];
    const float* a   = (const float*)d_in[3];
    float* out = (float*)d_out;

    char* ws = (char*)d_ws;
    unsigned short* WhT = (unsigned short*)ws;               // 2 MB
    float* u     = (float*)(ws + 2097152);
    float* v     = u + 128;
    float* e_src = (float*)(ws + 2097152 + 1024);
    float* e_dst = e_src + NN;
    float* num_ws = (float*)(ws + 4194304);                  // 32 MB
    float* den_ws = (float*)(ws + 4194304 + 33554432);       // 256 KB

    k0_uv<<<dim3(128), dim3(128), 0, stream>>>(W, a, u, v);
    k1_wh<<<dim3(256), dim3(256), 0, stream>>>(h, W, u, v, WhT, e_src, e_dst);
    k2_gat<<<dim3((NN / 128) * SEGS), dim3(512), 0, stream>>>(adj, WhT, e_src, e_dst, num_ws, den_ws);
    k3_merge<<<dim3(NN * FF / 4 / 256), dim3(256), 0, stream>>>(num_ws, den_ws, out);
}